// Round 3
// baseline (196.826 us; speedup 1.0000x reference)
//
#include <hip/hip_runtime.h>

// Embedding gather: out[token, :] = w[x[token], :]
// B=8, S=2048 -> 16384 tokens; DIM=1024 fp32; VOCAB=32000.
//
// v2b: latency/dispatch-bound fix (v2 + nontemporal-store type fix).
//  - 2048 blocks (8/CU) instead of 16384: amortize workgroup launch overhead.
//  - Each block handles 8 contiguous tokens; all 8 row-gathers issued
//    back-to-back (independent 16B loads -> 8 KiB in flight per wave)
//    before any store waits on them.
//  - Token ids loaded with uniform addresses -> compiler emits scalar loads.
//  - Nontemporal stores for `out` (write-once) to keep `w` hot in L2/L3.
//    __builtin_nontemporal_store requires a native vector type, not
//    HIP_vector_type -> use ext_vector_type(4).
typedef float floatx4 __attribute__((ext_vector_type(4)));

constexpr int TPB = 256;           // 256 threads x 16B = 4 KiB = one row
constexpr int TOK_PER_BLK = 8;

__global__ __launch_bounds__(TPB) void embed_gather_kernel(
    const int* __restrict__ x, const float* __restrict__ w,
    float* __restrict__ out, int n_tokens) {
  const int tid = threadIdx.x;
  const int base = blockIdx.x * TOK_PER_BLK;
  if (base >= n_tokens) return;

  if (base + TOK_PER_BLK <= n_tokens) {
    // Fast path: full chunk of 8 tokens.
    int rows[TOK_PER_BLK];
#pragma unroll
    for (int i = 0; i < TOK_PER_BLK; ++i) rows[i] = x[base + i];

    floatx4 v[TOK_PER_BLK];
#pragma unroll
    for (int i = 0; i < TOK_PER_BLK; ++i) {
      const floatx4* src =
          reinterpret_cast<const floatx4*>(w + (size_t)rows[i] * 1024);
      v[i] = src[tid];  // 8 independent loads in flight
    }
#pragma unroll
    for (int i = 0; i < TOK_PER_BLK; ++i) {
      floatx4* dst = reinterpret_cast<floatx4*>(out + (size_t)(base + i) * 1024);
      __builtin_nontemporal_store(v[i], dst + tid);
    }
  } else {
    // Tail (not hit at n_tokens=16384, kept for generality).
    for (int t = base; t < n_tokens; ++t) {
      int row = x[t];
      const floatx4* src = reinterpret_cast<const floatx4*>(w + (size_t)row * 1024);
      floatx4* dst = reinterpret_cast<floatx4*>(out + (size_t)t * 1024);
      dst[tid] = src[tid];
    }
  }
}

extern "C" void kernel_launch(void* const* d_in, const int* in_sizes, int n_in,
                              void* d_out, int out_size, void* d_ws, size_t ws_size,
                              hipStream_t stream) {
  const int* x = (const int*)d_in[0];     // [B*S] int32 token ids
  const float* w = (const float*)d_in[1]; // [VOCAB, DIM] fp32
  float* out = (float*)d_out;             // [B*S, DIM] fp32
  int n_tokens = in_sizes[0];             // 16384
  int grid = (n_tokens + TOK_PER_BLK - 1) / TOK_PER_BLK;  // 2048
  embed_gather_kernel<<<grid, TPB, 0, stream>>>(x, w, out, n_tokens);
}